// Round 14
// baseline (220.930 us; speedup 1.0000x reference)
//
#include <hip/hip_runtime.h>

#define F 64
#define P 32
#define MAXD 10
#define NGRP 8  // dst-range groups for k_fill, mapped to XCDs via blockIdx&7 (perf hint only)

// ---- bf16 helpers (RTN pack; unpack via shift/mask) ----
__device__ __forceinline__ unsigned short f2bf(float f) {
  unsigned b = __float_as_uint(f);
  return (unsigned short)((b + 0x7FFFu + ((b >> 16) & 1u)) >> 16);
}
__device__ __forceinline__ unsigned pk2(float a, float b) {
  return (unsigned)f2bf(a) | ((unsigned)f2bf(b) << 16);
}
__device__ __forceinline__ float blo(unsigned u) { return __uint_as_float(u << 16); }
__device__ __forceinline__ float bhi(unsigned u) { return __uint_as_float(u & 0xFFFF0000u); }

// ---------------- zero-init ----------------
__global__ void k_zero(float4* __restrict__ p, int n4) {
  int i = blockIdx.x * blockDim.x + threadIdx.x;
  int stride = gridDim.x * blockDim.x;
  float4 z = make_float4(0.f, 0.f, 0.f, 0.f);
  for (int idx = i; idx < n4; idx += stride) p[idx] = z;
}

// ---------------- degree count: single pass ----------------
__global__ void k_count_deg(const int* __restrict__ dst, int* __restrict__ deg, int E) {
  int i = blockIdx.x * blockDim.x + threadIdx.x;
  int stride = gridDim.x * blockDim.x;
  int E4 = E >> 2;
  const int4* d4p = (const int4*)dst;
  for (int e4 = i; e4 < E4; e4 += stride) {
    int4 d = d4p[e4];
    atomicAdd(&deg[d.x], 1);
    atomicAdd(&deg[d.y], 1);
    atomicAdd(&deg[d.z], 1);
    atomicAdd(&deg[d.w], 1);
  }
  for (int e = (E & ~3) + i; e < E; e += stride) atomicAdd(&deg[dst[e]], 1);
}

// ---------------- per-block raw sums (256 nodes/block) ----------------
__global__ void k_bsum(const int* __restrict__ deg, int* __restrict__ bsum, int N) {
  __shared__ int s[256];
  int t = threadIdx.x;
  int n = blockIdx.x * 256 + t;
  s[t] = (n < N) ? deg[n] : 0;
  __syncthreads();
  for (int o = 128; o > 0; o >>= 1) {
    if (t < o) s[t] += s[t + o];
    __syncthreads();
  }
  if (t == 0) bsum[blockIdx.x] = s[0];
}

// ---------------- scan finalize: each block sums bsum[0..b) itself (NB <= 256) ----------------
__global__ void k_scan_fin(const int* __restrict__ deg, const int* __restrict__ bsum,
                           int* __restrict__ off, int* __restrict__ cur,
                           float* __restrict__ dinv, int N, int NB) {
  __shared__ int sb[256];
  __shared__ int s[256];
  int t = threadIdx.x;
  int b = blockIdx.x;
  sb[t] = (t < NB && t < b) ? bsum[t] : 0;
  __syncthreads();
  for (int o = 128; o > 0; o >>= 1) {
    if (t < o) sb[t] += sb[t + o];
    __syncthreads();
  }
  int base = sb[0];
  int n = b * 256 + t;
  int v = (n < N) ? deg[n] : 0;
  s[t] = v;
  __syncthreads();
  for (int o = 1; o < 256; o <<= 1) {
    int u = (t >= o) ? s[t - o] : 0;
    __syncthreads();
    s[t] += u;
    __syncthreads();
  }
  if (n < N) {
    int ex = base + s[t] - v;
    off[n] = ex;
    cur[n] = ex;
    dinv[n] = rsqrtf((float)(v + 1));
    if (n == N - 1) off[N] = ex + v;
  }
}

// ---------------- CSR fill, XCD-partitioned (csr scatter needs write locality) ----------------
__global__ void k_fill(const int* __restrict__ src, const int* __restrict__ dst,
                       int* __restrict__ cur, int* __restrict__ csr, int E, int N) {
  int r = blockIdx.x & (NGRP - 1);
  float scale = (float)NGRP / (float)N;
  int gblk = blockIdx.x >> 3;
  int i = gblk * blockDim.x + threadIdx.x;
  int stride = (gridDim.x >> 3) * blockDim.x;
  int E4 = E >> 2;
  const int4* d4p = (const int4*)dst;
  for (int e4 = i; e4 < E4; e4 += stride) {
    int4 d4 = d4p[e4];
    int e = e4 * 4;
    int rr;
    rr = min(NGRP - 1, (int)((float)d4.x * scale));
    if (rr == r) { int pos = atomicAdd(&cur[d4.x], 1); csr[pos] = src[e]; }
    rr = min(NGRP - 1, (int)((float)d4.y * scale));
    if (rr == r) { int pos = atomicAdd(&cur[d4.y], 1); csr[pos] = src[e + 1]; }
    rr = min(NGRP - 1, (int)((float)d4.z * scale));
    if (rr == r) { int pos = atomicAdd(&cur[d4.z], 1); csr[pos] = src[e + 2]; }
    rr = min(NGRP - 1, (int)((float)d4.w * scale));
    if (rr == r) { int pos = atomicAdd(&cur[d4.w], 1); csr[pos] = src[e + 3]; }
  }
  for (int e = (E & ~3) + i; e < E; e += stride) {
    int d = dst[e];
    int rr = min(NGRP - 1, (int)((float)d * scale));
    if (rr == r) { int pos = atomicAdd(&cur[d], 1); csr[pos] = src[e]; }
  }
}

// ---------------- xs16 = bf16(dinv[n] * x[n]) ----------------
__global__ void k_scale16(const float* __restrict__ x, const float* __restrict__ dinv,
                          uint2* __restrict__ xs, int N) {
  int i = blockIdx.x * blockDim.x + threadIdx.x;
  int stride = gridDim.x * blockDim.x;
  int tot = N * (F / 4);
  const float4* x4 = (const float4*)x;
  for (int idx = i; idx < tot; idx += stride) {
    int n = idx >> 4;
    float d = dinv[n];
    float4 v = x4[idx];
    uint2 p;
    p.x = pk2(v.x * d, v.y * d);
    p.y = pk2(v.z * d, v.w * d);
    xs[idx] = p;
  }
}

// readlane: compile-time source lane (after unroll)
__device__ __forceinline__ float rdlane(float v, int srclane) {
  return __int_as_float(__builtin_amdgcn_readlane(__float_as_int(v), srclane));
}

__device__ __forceinline__ void addbf(float4& a, uint2 p) {
  a.x += blo(p.x); a.y += bhi(p.x); a.z += blo(p.y); a.w += bhi(p.y);
}

// ---------------- fused GCN layer: bf16 gather (8-deep MLP) + fp32 GEMV, node-per-group ------
template <bool WRITE_SCALED>
__global__ void k_gcn(const unsigned* __restrict__ xs, const int* __restrict__ csr,
                      const int* __restrict__ off, const float* __restrict__ dinv,
                      const float* __restrict__ W, const float* __restrict__ bias,
                      unsigned short* __restrict__ out, int N) {
  int wid = (blockIdx.x * blockDim.x + threadIdx.x) >> 6;
  int lane = threadIdx.x & 63;
  int nwaves = (gridDim.x * blockDim.x) >> 6;
  int g = lane >> 4, l = lane & 15;
  float w[F];
#pragma unroll
  for (int k = 0; k < F; ++k) w[k] = W[k * F + lane];  // W column `lane`
  float bv = bias[lane];
  for (int base = wid * 4; base < N; base += nwaves * 4) {
    int n = min(base + g, N - 1);
    int e0 = off[n], e1 = off[n + 1];
    float dnode = dinv[n];
    float4 acc = make_float4(0.f, 0.f, 0.f, 0.f);
    addbf(acc, *(const uint2*)&xs[(size_t)n * 32 + l * 2]);  // self term
    for (int win = e0; win < e1; win += 16) {
      int m = min(16, e1 - win);
      int ce = (win + l < e1) ? csr[win + l] : 0;  // 16 contiguous edges, coalesced
      int j = 0;
      for (; j + 8 <= m; j += 8) {  // 8 rows in flight per group (32/wave)
        int s0 = __shfl(ce, g * 16 + j + 0, 64);
        int s1 = __shfl(ce, g * 16 + j + 1, 64);
        int s2 = __shfl(ce, g * 16 + j + 2, 64);
        int s3 = __shfl(ce, g * 16 + j + 3, 64);
        int s4 = __shfl(ce, g * 16 + j + 4, 64);
        int s5 = __shfl(ce, g * 16 + j + 5, 64);
        int s6 = __shfl(ce, g * 16 + j + 6, 64);
        int s7 = __shfl(ce, g * 16 + j + 7, 64);
        uint2 q0 = *(const uint2*)&xs[(size_t)s0 * 32 + l * 2];
        uint2 q1 = *(const uint2*)&xs[(size_t)s1 * 32 + l * 2];
        uint2 q2 = *(const uint2*)&xs[(size_t)s2 * 32 + l * 2];
        uint2 q3 = *(const uint2*)&xs[(size_t)s3 * 32 + l * 2];
        uint2 q4 = *(const uint2*)&xs[(size_t)s4 * 32 + l * 2];
        uint2 q5 = *(const uint2*)&xs[(size_t)s5 * 32 + l * 2];
        uint2 q6 = *(const uint2*)&xs[(size_t)s6 * 32 + l * 2];
        uint2 q7 = *(const uint2*)&xs[(size_t)s7 * 32 + l * 2];
        addbf(acc, q0); addbf(acc, q1); addbf(acc, q2); addbf(acc, q3);
        addbf(acc, q4); addbf(acc, q5); addbf(acc, q6); addbf(acc, q7);
      }
      for (; j + 4 <= m; j += 4) {
        int s0 = __shfl(ce, g * 16 + j + 0, 64);
        int s1 = __shfl(ce, g * 16 + j + 1, 64);
        int s2 = __shfl(ce, g * 16 + j + 2, 64);
        int s3 = __shfl(ce, g * 16 + j + 3, 64);
        uint2 q0 = *(const uint2*)&xs[(size_t)s0 * 32 + l * 2];
        uint2 q1 = *(const uint2*)&xs[(size_t)s1 * 32 + l * 2];
        uint2 q2 = *(const uint2*)&xs[(size_t)s2 * 32 + l * 2];
        uint2 q3 = *(const uint2*)&xs[(size_t)s3 * 32 + l * 2];
        addbf(acc, q0); addbf(acc, q1); addbf(acc, q2); addbf(acc, q3);
      }
      for (; j < m; ++j) {
        int s = __shfl(ce, g * 16 + j, 64);
        addbf(acc, *(const uint2*)&xs[(size_t)s * 32 + l * 2]);
      }
    }
    // GEMV per node (gg compile-time after unroll -> readlane legal)
#pragma unroll
    for (int gg = 0; gg < 4; ++gg) {
      float y0 = 0.f, y1 = 0.f, y2 = 0.f, y3 = 0.f;
#pragma unroll
      for (int k = 0; k < F; k += 4) {
        y0 += rdlane(acc.x, gg * 16 + (k >> 2)) * w[k + 0];
        y1 += rdlane(acc.y, gg * 16 + (k >> 2)) * w[k + 1];
        y2 += rdlane(acc.z, gg * 16 + (k >> 2)) * w[k + 2];
        y3 += rdlane(acc.w, gg * 16 + (k >> 2)) * w[k + 3];
      }
      float dd = rdlane(dnode, gg * 16);
      float y = dd * ((y0 + y1) + (y2 + y3)) + bv;
      if (WRITE_SCALED) y *= dd;
      int nn = base + gg;
      if (nn < N) out[(size_t)nn * F + lane] = f2bf(y);
    }
  }
}

// ---------------- fused MFConv + policy agg + POOLING (4-deep gather; batch sorted) ----------
// block = 16 consecutive nodes -> usually 1-2 graphs: 2-slot LDS accumulator + global fallback.
// __launch_bounds__(256,4): cap at 4 waves/EU -> VGPR budget 128, keeps 4 gathers in flight
// (R11/R13 lesson: default allocation starved this kernel to 32-40 VGPR and serialized loads).
__global__ void __launch_bounds__(256, 4)
k_mfpol(const unsigned* __restrict__ H, const int* __restrict__ csr,
        const int* __restrict__ off, const float* __restrict__ dinv,
        const float* __restrict__ Wl, const float* __restrict__ bl,
        const float* __restrict__ Wr, const int* __restrict__ batch,
        float* __restrict__ Uacc, float* __restrict__ valg,
        float* __restrict__ cntg, int N, int G) {
  __shared__ float Ua[2][64];
  __shared__ float va[2], ca[2];
  int t = threadIdx.x;
  if (t < 128) Ua[t >> 6][t & 63] = 0.f;
  if (t < 2) { va[t] = 0.f; ca[t] = 0.f; }
  __syncthreads();
  int base16 = blockIdx.x * 16;
  int gmin = batch[base16];
  int lane = t & 63;
  int g = lane >> 4, l = lane & 15;
  int ni = (t >> 6) * 4 + g;  // node slot in block 0..15
  bool valid = (base16 + ni) < N;
  int n = valid ? base16 + ni : N - 1;
  int e0 = off[n], e1 = off[n + 1];
  float dn = dinv[n];
  float4 ah = make_float4(0.f, 0.f, 0.f, 0.f);
  float4 aw = make_float4(0.f, 0.f, 0.f, 0.f);
  for (int win = e0; win < e1; win += 16) {
    int m = min(16, e1 - win);
    bool p = (win + l < e1);
    int ce = p ? csr[win + l] : 0;
    float cd = p ? dinv[ce] : 0.f;
    int j = 0;
    for (; j + 4 <= m; j += 4) {
      int s0 = __shfl(ce, g * 16 + j + 0, 64);
      int s1 = __shfl(ce, g * 16 + j + 1, 64);
      int s2 = __shfl(ce, g * 16 + j + 2, 64);
      int s3 = __shfl(ce, g * 16 + j + 3, 64);
      float d0 = __shfl(cd, g * 16 + j + 0, 64);
      float d1 = __shfl(cd, g * 16 + j + 1, 64);
      float d2 = __shfl(cd, g * 16 + j + 2, 64);
      float d3 = __shfl(cd, g * 16 + j + 3, 64);
      uint2 q0 = *(const uint2*)&H[(size_t)s0 * 32 + l * 2];
      uint2 q1 = *(const uint2*)&H[(size_t)s1 * 32 + l * 2];
      uint2 q2 = *(const uint2*)&H[(size_t)s2 * 32 + l * 2];
      uint2 q3 = *(const uint2*)&H[(size_t)s3 * 32 + l * 2];
      float f0x = blo(q0.x), f0y = bhi(q0.x), f0z = blo(q0.y), f0w = bhi(q0.y);
      float f1x = blo(q1.x), f1y = bhi(q1.x), f1z = blo(q1.y), f1w = bhi(q1.y);
      float f2x = blo(q2.x), f2y = bhi(q2.x), f2z = blo(q2.y), f2w = bhi(q2.y);
      float f3x = blo(q3.x), f3y = bhi(q3.x), f3z = blo(q3.y), f3w = bhi(q3.y);
      ah.x += (f0x + f1x) + (f2x + f3x);
      ah.y += (f0y + f1y) + (f2y + f3y);
      ah.z += (f0z + f1z) + (f2z + f3z);
      ah.w += (f0w + f1w) + (f2w + f3w);
      aw.x += (d0 * f0x + d1 * f1x) + (d2 * f2x + d3 * f3x);
      aw.y += (d0 * f0y + d1 * f1y) + (d2 * f2y + d3 * f3y);
      aw.z += (d0 * f0z + d1 * f1z) + (d2 * f2z + d3 * f3z);
      aw.w += (d0 * f0w + d1 * f1w) + (d2 * f2w + d3 * f3w);
    }
    for (; j < m; ++j) {
      int s = __shfl(ce, g * 16 + j, 64);
      float dd = __shfl(cd, g * 16 + j, 64);
      uint2 q = *(const uint2*)&H[(size_t)s * 32 + l * 2];
      float fx = blo(q.x), fy = bhi(q.x), fz = blo(q.y), fw = bhi(q.y);
      ah.x += fx; ah.y += fy; ah.z += fz; ah.w += fw;
      aw.x += dd * fx; aw.y += dd * fy; aw.z += dd * fz; aw.w += dd * fw;
    }
  }
  int dc = min(e1 - e0, MAXD);
  uint2 qn = *(const uint2*)&H[(size_t)n * 32 + l * 2];
  float4 hn = make_float4(blo(qn.x), bhi(qn.x), blo(qn.y), bhi(qn.y));
  float4 wl4 = *(const float4*)&Wl[dc * F + l * 4];
  float4 wr4 = *(const float4*)&Wr[dc * F + l * 4];
  float part = ah.x * wl4.x + ah.y * wl4.y + ah.z * wl4.z + ah.w * wl4.w
             + hn.x * wr4.x + hn.y * wr4.y + hn.z * wr4.z + hn.w * wr4.w;
#pragma unroll
  for (int o = 1; o < 16; o <<= 1) part += __shfl_xor(part, o, 64);  // in-group reduce
  float vout = part + bl[dc];
  float4 r;
  r.x = (aw.x + dn * hn.x) * dn;
  r.y = (aw.y + dn * hn.y) * dn;
  r.z = (aw.z + dn * hn.z) * dn;
  r.w = (aw.w + dn * hn.w) * dn;
  if (valid) {
    int bg = batch[n];
    int slot = bg - gmin;
    if (slot < 2) {
      atomicAdd(&Ua[slot][l * 4 + 0], r.x);
      atomicAdd(&Ua[slot][l * 4 + 1], r.y);
      atomicAdd(&Ua[slot][l * 4 + 2], r.z);
      atomicAdd(&Ua[slot][l * 4 + 3], r.w);
      if (l == 0) { atomicAdd(&va[slot], vout); atomicAdd(&ca[slot], 1.f); }
    } else {  // pathological tiny-graph span: direct global fallback
      atomicAdd(&Uacc[bg * F + l * 4 + 0], r.x);
      atomicAdd(&Uacc[bg * F + l * 4 + 1], r.y);
      atomicAdd(&Uacc[bg * F + l * 4 + 2], r.z);
      atomicAdd(&Uacc[bg * F + l * 4 + 3], r.w);
      if (l == 0) { atomicAdd(&valg[bg], vout); atomicAdd(&cntg[bg], 1.f); }
    }
  }
  __syncthreads();
  if (t < 128) {
    int slot = t >> 6, f = t & 63;
    int bg = gmin + slot;
    if (bg < G) {
      atomicAdd(&Uacc[bg * F + f], Ua[slot][f]);
      if (f == 0) { atomicAdd(&valg[bg], va[slot]); atomicAdd(&cntg[bg], ca[slot]); }
    }
  }
}

// ---------------- finalize ----------------
__global__ void k_polfin(const float* __restrict__ Uacc, const float* __restrict__ valg,
                         const float* __restrict__ cntg, const float* __restrict__ W_pol,
                         const float* __restrict__ b_pol, float* __restrict__ out, int G) {
  int i = blockIdx.x * blockDim.x + threadIdx.x;
  if (i < G * P) {
    int g = i >> 5, p = i & 31;
    float s = 0.f;
#pragma unroll
    for (int k = 0; k < F; ++k) s += Uacc[g * F + k] * W_pol[k * P + p];
    out[i] = s / fmaxf(cntg[g], 1.f) + b_pol[p];
  }
  if (i < G) out[(size_t)G * P + i] = valg[i];
}

extern "C" void kernel_launch(void* const* d_in, const int* in_sizes, int n_in,
                              void* d_out, int out_size, void* d_ws, size_t ws_size,
                              hipStream_t stream) {
  const float* x = (const float*)d_in[0];
  const int* ei = (const int*)d_in[1];
  const int* batch = (const int*)d_in[2];
  const float* W_in = (const float*)d_in[3];
  const float* b_in = (const float*)d_in[4];
  const float* W1 = (const float*)d_in[5];
  const float* b1 = (const float*)d_in[6];
  const float* Wl = (const float*)d_in[7];
  const float* bl = (const float*)d_in[8];
  const float* Wr = (const float*)d_in[9];
  const float* W_pol = (const float*)d_in[10];
  const float* b_pol = (const float*)d_in[11];
  float* out = (float*)d_out;

  const int N = in_sizes[0] / F;
  const int E = in_sizes[1] / 2;
  const int G = out_size / (P + 1);
  const int* esrc = ei;
  const int* edst = ei + E;
  const int NB = (N + 255) / 256;  // 196 for N=50000; k_scan_fin assumes NB <= 256

  char* ws = (char*)d_ws;
  size_t o = 0;
  auto alloc = [&](size_t bytes) {
    char* r = ws + o;
    o = (o + bytes + 255) & ~(size_t)255;
    return r;
  };
  // ---- zero-init zone ----
  char* zbase = ws;
  int* deg = (int*)alloc((size_t)N * 4);
  float* Uacc = (float*)alloc((size_t)G * F * 4);
  float* valg = (float*)alloc((size_t)G * 4);
  float* cntg = (float*)alloc((size_t)G * 4);
  size_t zbytes = o;  // multiple of 256
  // ---- rest ----
  int* off = (int*)alloc((size_t)(N + 1) * 4);
  int* cur = (int*)alloc((size_t)N * 4);
  float* dinv = (float*)alloc((size_t)N * 4);
  int* csr = (int*)alloc((size_t)E * 4);
  int* bsum = (int*)alloc(1024 * 4);
  unsigned* xs16 = (unsigned*)alloc((size_t)N * F * 2);  // bf16 x*dinv
  unsigned* t16 = (unsigned*)alloc((size_t)N * F * 2);   // bf16 dinv*h1
  unsigned* h16 = (unsigned*)alloc((size_t)N * F * 2);   // bf16 h2
  (void)ws_size; (void)n_in;

  const int bs = 256;
  int zn4 = (int)(zbytes / 16);
  k_zero<<<(zn4 + bs - 1) / bs, bs, 0, stream>>>((float4*)zbase, zn4);

  k_count_deg<<<1024, bs, 0, stream>>>(edst, deg, E);
  k_bsum<<<NB, bs, 0, stream>>>(deg, bsum, N);
  k_scan_fin<<<NB, bs, 0, stream>>>(deg, bsum, off, cur, dinv, N, NB);
  k_fill<<<2048, bs, 0, stream>>>(esrc, edst, cur, csr, E, N);

  // xs16 = bf16(dinv * x)
  k_scale16<<<2048, bs, 0, stream>>>(x, dinv, (uint2*)xs16, N);

  // GCN layers: 2048 blocks (8192 waves = full residency), 8-deep gather unroll
  k_gcn<true><<<2048, bs, 0, stream>>>(xs16, csr, off, dinv, W_in, b_in,
                                       (unsigned short*)t16, N);
  k_gcn<false><<<2048, bs, 0, stream>>>(t16, csr, off, dinv, W1, b1,
                                        (unsigned short*)h16, N);

  // fused MFConv + policy aggregation + pooling (exact grid: block = 16 consecutive nodes)
  int mfBlocks = (N + 15) / 16;
  k_mfpol<<<mfBlocks, bs, 0, stream>>>(h16, csr, off, dinv, Wl, bl, Wr, batch,
                                       Uacc, valg, cntg, N, G);

  k_polfin<<<(G * P + bs - 1) / bs, bs, 0, stream>>>(Uacc, valg, cntg, W_pol, b_pol, out, G);
}

// Round 15
// 206.423 us; speedup vs baseline: 1.0703x; 1.0703x over previous
//
#include <hip/hip_runtime.h>

#define F 64
#define P 32
#define MAXD 10
#define NGRP 8  // dst-range groups for k_fill, mapped to XCDs via blockIdx&7 (perf hint only)

// ---- bf16 helpers (RTN pack; unpack via shift/mask) ----
__device__ __forceinline__ unsigned short f2bf(float f) {
  unsigned b = __float_as_uint(f);
  return (unsigned short)((b + 0x7FFFu + ((b >> 16) & 1u)) >> 16);
}
__device__ __forceinline__ unsigned pk2(float a, float b) {
  return (unsigned)f2bf(a) | ((unsigned)f2bf(b) << 16);
}
__device__ __forceinline__ float blo(unsigned u) { return __uint_as_float(u << 16); }
__device__ __forceinline__ float bhi(unsigned u) { return __uint_as_float(u & 0xFFFF0000u); }

// ---------------- zero-init ----------------
__global__ void k_zero(float4* __restrict__ p, int n4) {
  int i = blockIdx.x * blockDim.x + threadIdx.x;
  int stride = gridDim.x * blockDim.x;
  float4 z = make_float4(0.f, 0.f, 0.f, 0.f);
  for (int idx = i; idx < n4; idx += stride) p[idx] = z;
}

// ---------------- degree count: single pass ----------------
__global__ void k_count_deg(const int* __restrict__ dst, int* __restrict__ deg, int E) {
  int i = blockIdx.x * blockDim.x + threadIdx.x;
  int stride = gridDim.x * blockDim.x;
  int E4 = E >> 2;
  const int4* d4p = (const int4*)dst;
  for (int e4 = i; e4 < E4; e4 += stride) {
    int4 d = d4p[e4];
    atomicAdd(&deg[d.x], 1);
    atomicAdd(&deg[d.y], 1);
    atomicAdd(&deg[d.z], 1);
    atomicAdd(&deg[d.w], 1);
  }
  for (int e = (E & ~3) + i; e < E; e += stride) atomicAdd(&deg[dst[e]], 1);
}

// ---------------- per-block raw sums (256 nodes/block) ----------------
__global__ void k_bsum(const int* __restrict__ deg, int* __restrict__ bsum, int N) {
  __shared__ int s[256];
  int t = threadIdx.x;
  int n = blockIdx.x * 256 + t;
  s[t] = (n < N) ? deg[n] : 0;
  __syncthreads();
  for (int o = 128; o > 0; o >>= 1) {
    if (t < o) s[t] += s[t + o];
    __syncthreads();
  }
  if (t == 0) bsum[blockIdx.x] = s[0];
}

// ---------------- scan finalize: each block sums bsum[0..b) itself (NB <= 256) ----------------
__global__ void k_scan_fin(const int* __restrict__ deg, const int* __restrict__ bsum,
                           int* __restrict__ off, int* __restrict__ cur,
                           float* __restrict__ dinv, int N, int NB) {
  __shared__ int sb[256];
  __shared__ int s[256];
  int t = threadIdx.x;
  int b = blockIdx.x;
  sb[t] = (t < NB && t < b) ? bsum[t] : 0;
  __syncthreads();
  for (int o = 128; o > 0; o >>= 1) {
    if (t < o) sb[t] += sb[t + o];
    __syncthreads();
  }
  int base = sb[0];
  int n = b * 256 + t;
  int v = (n < N) ? deg[n] : 0;
  s[t] = v;
  __syncthreads();
  for (int o = 1; o < 256; o <<= 1) {
    int u = (t >= o) ? s[t - o] : 0;
    __syncthreads();
    s[t] += u;
    __syncthreads();
  }
  if (n < N) {
    int ex = base + s[t] - v;
    off[n] = ex;
    cur[n] = ex;
    dinv[n] = rsqrtf((float)(v + 1));
    if (n == N - 1) off[N] = ex + v;
  }
}

// ---------------- CSR fill, XCD-partitioned (csr scatter needs write locality) ----------------
__global__ void k_fill(const int* __restrict__ src, const int* __restrict__ dst,
                       int* __restrict__ cur, int* __restrict__ csr, int E, int N) {
  int r = blockIdx.x & (NGRP - 1);
  float scale = (float)NGRP / (float)N;
  int gblk = blockIdx.x >> 3;
  int i = gblk * blockDim.x + threadIdx.x;
  int stride = (gridDim.x >> 3) * blockDim.x;
  int E4 = E >> 2;
  const int4* d4p = (const int4*)dst;
  for (int e4 = i; e4 < E4; e4 += stride) {
    int4 d4 = d4p[e4];
    int e = e4 * 4;
    int rr;
    rr = min(NGRP - 1, (int)((float)d4.x * scale));
    if (rr == r) { int pos = atomicAdd(&cur[d4.x], 1); csr[pos] = src[e]; }
    rr = min(NGRP - 1, (int)((float)d4.y * scale));
    if (rr == r) { int pos = atomicAdd(&cur[d4.y], 1); csr[pos] = src[e + 1]; }
    rr = min(NGRP - 1, (int)((float)d4.z * scale));
    if (rr == r) { int pos = atomicAdd(&cur[d4.z], 1); csr[pos] = src[e + 2]; }
    rr = min(NGRP - 1, (int)((float)d4.w * scale));
    if (rr == r) { int pos = atomicAdd(&cur[d4.w], 1); csr[pos] = src[e + 3]; }
  }
  for (int e = (E & ~3) + i; e < E; e += stride) {
    int d = dst[e];
    int rr = min(NGRP - 1, (int)((float)d * scale));
    if (rr == r) { int pos = atomicAdd(&cur[d], 1); csr[pos] = src[e]; }
  }
}

// ---------------- xs16 = bf16(dinv[n] * x[n]) ----------------
__global__ void k_scale16(const float* __restrict__ x, const float* __restrict__ dinv,
                          uint2* __restrict__ xs, int N) {
  int i = blockIdx.x * blockDim.x + threadIdx.x;
  int stride = gridDim.x * blockDim.x;
  int tot = N * (F / 4);
  const float4* x4 = (const float4*)x;
  for (int idx = i; idx < tot; idx += stride) {
    int n = idx >> 4;
    float d = dinv[n];
    float4 v = x4[idx];
    uint2 p;
    p.x = pk2(v.x * d, v.y * d);
    p.y = pk2(v.z * d, v.w * d);
    xs[idx] = p;
  }
}

// readlane: compile-time source lane (after unroll)
__device__ __forceinline__ float rdlane(float v, int srclane) {
  return __int_as_float(__builtin_amdgcn_readlane(__float_as_int(v), srclane));
}

__device__ __forceinline__ void addbf(float4& a, uint2 p) {
  a.x += blo(p.x); a.y += bhi(p.x); a.z += blo(p.y); a.w += bhi(p.y);
}

// ---------------- fused GCN layer: bf16 gather (8-deep MLP) + fp32 GEMV, node-per-group ------
template <bool WRITE_SCALED>
__global__ void k_gcn(const unsigned* __restrict__ xs, const int* __restrict__ csr,
                      const int* __restrict__ off, const float* __restrict__ dinv,
                      const float* __restrict__ W, const float* __restrict__ bias,
                      unsigned short* __restrict__ out, int N) {
  int wid = (blockIdx.x * blockDim.x + threadIdx.x) >> 6;
  int lane = threadIdx.x & 63;
  int nwaves = (gridDim.x * blockDim.x) >> 6;
  int g = lane >> 4, l = lane & 15;
  float w[F];
#pragma unroll
  for (int k = 0; k < F; ++k) w[k] = W[k * F + lane];  // W column `lane`
  float bv = bias[lane];
  for (int base = wid * 4; base < N; base += nwaves * 4) {
    int n = min(base + g, N - 1);
    int e0 = off[n], e1 = off[n + 1];
    float dnode = dinv[n];
    float4 acc = make_float4(0.f, 0.f, 0.f, 0.f);
    addbf(acc, *(const uint2*)&xs[(size_t)n * 32 + l * 2]);  // self term
    for (int win = e0; win < e1; win += 16) {
      int m = min(16, e1 - win);
      int ce = (win + l < e1) ? csr[win + l] : 0;  // 16 contiguous edges, coalesced
      int j = 0;
      for (; j + 8 <= m; j += 8) {  // 8 rows in flight per group (32/wave)
        int s0 = __shfl(ce, g * 16 + j + 0, 64);
        int s1 = __shfl(ce, g * 16 + j + 1, 64);
        int s2 = __shfl(ce, g * 16 + j + 2, 64);
        int s3 = __shfl(ce, g * 16 + j + 3, 64);
        int s4 = __shfl(ce, g * 16 + j + 4, 64);
        int s5 = __shfl(ce, g * 16 + j + 5, 64);
        int s6 = __shfl(ce, g * 16 + j + 6, 64);
        int s7 = __shfl(ce, g * 16 + j + 7, 64);
        uint2 q0 = *(const uint2*)&xs[(size_t)s0 * 32 + l * 2];
        uint2 q1 = *(const uint2*)&xs[(size_t)s1 * 32 + l * 2];
        uint2 q2 = *(const uint2*)&xs[(size_t)s2 * 32 + l * 2];
        uint2 q3 = *(const uint2*)&xs[(size_t)s3 * 32 + l * 2];
        uint2 q4 = *(const uint2*)&xs[(size_t)s4 * 32 + l * 2];
        uint2 q5 = *(const uint2*)&xs[(size_t)s5 * 32 + l * 2];
        uint2 q6 = *(const uint2*)&xs[(size_t)s6 * 32 + l * 2];
        uint2 q7 = *(const uint2*)&xs[(size_t)s7 * 32 + l * 2];
        addbf(acc, q0); addbf(acc, q1); addbf(acc, q2); addbf(acc, q3);
        addbf(acc, q4); addbf(acc, q5); addbf(acc, q6); addbf(acc, q7);
      }
      for (; j + 4 <= m; j += 4) {
        int s0 = __shfl(ce, g * 16 + j + 0, 64);
        int s1 = __shfl(ce, g * 16 + j + 1, 64);
        int s2 = __shfl(ce, g * 16 + j + 2, 64);
        int s3 = __shfl(ce, g * 16 + j + 3, 64);
        uint2 q0 = *(const uint2*)&xs[(size_t)s0 * 32 + l * 2];
        uint2 q1 = *(const uint2*)&xs[(size_t)s1 * 32 + l * 2];
        uint2 q2 = *(const uint2*)&xs[(size_t)s2 * 32 + l * 2];
        uint2 q3 = *(const uint2*)&xs[(size_t)s3 * 32 + l * 2];
        addbf(acc, q0); addbf(acc, q1); addbf(acc, q2); addbf(acc, q3);
      }
      for (; j < m; ++j) {
        int s = __shfl(ce, g * 16 + j, 64);
        addbf(acc, *(const uint2*)&xs[(size_t)s * 32 + l * 2]);
      }
    }
    // GEMV per node (gg compile-time after unroll -> readlane legal)
#pragma unroll
    for (int gg = 0; gg < 4; ++gg) {
      float y0 = 0.f, y1 = 0.f, y2 = 0.f, y3 = 0.f;
#pragma unroll
      for (int k = 0; k < F; k += 4) {
        y0 += rdlane(acc.x, gg * 16 + (k >> 2)) * w[k + 0];
        y1 += rdlane(acc.y, gg * 16 + (k >> 2)) * w[k + 1];
        y2 += rdlane(acc.z, gg * 16 + (k >> 2)) * w[k + 2];
        y3 += rdlane(acc.w, gg * 16 + (k >> 2)) * w[k + 3];
      }
      float dd = rdlane(dnode, gg * 16);
      float y = dd * ((y0 + y1) + (y2 + y3)) + bv;
      if (WRITE_SCALED) y *= dd;
      int nn = base + gg;
      if (nn < N) out[(size_t)nn * F + lane] = f2bf(y);
    }
  }
}

// ---------------- fused MFConv + policy aggregation, bf16 gather (4-deep; unfused: R12) ------
__global__ void k_mfpol(const unsigned* __restrict__ H, const int* __restrict__ csr,
                        const int* __restrict__ off, const float* __restrict__ dinv,
                        const float* __restrict__ Wl, const float* __restrict__ bl,
                        const float* __restrict__ Wr, float* __restrict__ val,
                        float* __restrict__ u, int N) {
  int wid = (blockIdx.x * blockDim.x + threadIdx.x) >> 6;
  int lane = threadIdx.x & 63;
  int nwaves = (gridDim.x * blockDim.x) >> 6;
  int g = lane >> 4, l = lane & 15;
  for (int base = wid * 4; base < N; base += nwaves * 4) {
    bool valid = (base + g) < N;
    int n = min(base + g, N - 1);
    int e0 = off[n], e1 = off[n + 1];
    float dn = dinv[n];
    float4 ah = make_float4(0.f, 0.f, 0.f, 0.f);
    float4 aw = make_float4(0.f, 0.f, 0.f, 0.f);
    for (int win = e0; win < e1; win += 16) {
      int m = min(16, e1 - win);
      bool p = (win + l < e1);
      int ce = p ? csr[win + l] : 0;
      float cd = p ? dinv[ce] : 0.f;
      int j = 0;
      for (; j + 4 <= m; j += 4) {
        int s0 = __shfl(ce, g * 16 + j + 0, 64);
        int s1 = __shfl(ce, g * 16 + j + 1, 64);
        int s2 = __shfl(ce, g * 16 + j + 2, 64);
        int s3 = __shfl(ce, g * 16 + j + 3, 64);
        float d0 = __shfl(cd, g * 16 + j + 0, 64);
        float d1 = __shfl(cd, g * 16 + j + 1, 64);
        float d2 = __shfl(cd, g * 16 + j + 2, 64);
        float d3 = __shfl(cd, g * 16 + j + 3, 64);
        uint2 q0 = *(const uint2*)&H[(size_t)s0 * 32 + l * 2];
        uint2 q1 = *(const uint2*)&H[(size_t)s1 * 32 + l * 2];
        uint2 q2 = *(const uint2*)&H[(size_t)s2 * 32 + l * 2];
        uint2 q3 = *(const uint2*)&H[(size_t)s3 * 32 + l * 2];
        float f0x = blo(q0.x), f0y = bhi(q0.x), f0z = blo(q0.y), f0w = bhi(q0.y);
        float f1x = blo(q1.x), f1y = bhi(q1.x), f1z = blo(q1.y), f1w = bhi(q1.y);
        float f2x = blo(q2.x), f2y = bhi(q2.x), f2z = blo(q2.y), f2w = bhi(q2.y);
        float f3x = blo(q3.x), f3y = bhi(q3.x), f3z = blo(q3.y), f3w = bhi(q3.y);
        ah.x += (f0x + f1x) + (f2x + f3x);
        ah.y += (f0y + f1y) + (f2y + f3y);
        ah.z += (f0z + f1z) + (f2z + f3z);
        ah.w += (f0w + f1w) + (f2w + f3w);
        aw.x += (d0 * f0x + d1 * f1x) + (d2 * f2x + d3 * f3x);
        aw.y += (d0 * f0y + d1 * f1y) + (d2 * f2y + d3 * f3y);
        aw.z += (d0 * f0z + d1 * f1z) + (d2 * f2z + d3 * f3z);
        aw.w += (d0 * f0w + d1 * f1w) + (d2 * f2w + d3 * f3w);
      }
      for (; j < m; ++j) {
        int s = __shfl(ce, g * 16 + j, 64);
        float dd = __shfl(cd, g * 16 + j, 64);
        uint2 q = *(const uint2*)&H[(size_t)s * 32 + l * 2];
        float fx = blo(q.x), fy = bhi(q.x), fz = blo(q.y), fw = bhi(q.y);
        ah.x += fx; ah.y += fy; ah.z += fz; ah.w += fw;
        aw.x += dd * fx; aw.y += dd * fy; aw.z += dd * fz; aw.w += dd * fw;
      }
    }
    int dc = min(e1 - e0, MAXD);
    uint2 qn = *(const uint2*)&H[(size_t)n * 32 + l * 2];
    float4 hn = make_float4(blo(qn.x), bhi(qn.x), blo(qn.y), bhi(qn.y));
    float4 wl4 = *(const float4*)&Wl[dc * F + l * 4];
    float4 wr4 = *(const float4*)&Wr[dc * F + l * 4];
    float part = ah.x * wl4.x + ah.y * wl4.y + ah.z * wl4.z + ah.w * wl4.w
               + hn.x * wr4.x + hn.y * wr4.y + hn.z * wr4.z + hn.w * wr4.w;
#pragma unroll
    for (int o = 1; o < 16; o <<= 1) part += __shfl_xor(part, o, 64);  // in-group reduce
    if (l == 0 && valid) val[n] = part + bl[dc];
    if (valid) {
      float4 r;
      r.x = (aw.x + dn * hn.x) * dn;
      r.y = (aw.y + dn * hn.y) * dn;
      r.z = (aw.z + dn * hn.z) * dn;
      r.w = (aw.w + dn * hn.w) * dn;
      *(float4*)&u[(size_t)n * F + l * 4] = r;
    }
  }
}

// ---------------- pooling (batch sorted) ----------------
__global__ void k_pool2(const float* __restrict__ u, const float* __restrict__ valn,
                        const int* __restrict__ batch, float* __restrict__ Uacc,
                        float* __restrict__ valg, float* __restrict__ cntg, int N) {
  __shared__ float Ul[64 * F];
  __shared__ float Vl[64], Cl[64];
  int t = threadIdx.x;
  for (int i = t; i < 64 * F; i += 256) Ul[i] = 0.f;
  if (t < 64) { Vl[t] = 0.f; Cl[t] = 0.f; }
  __syncthreads();
  int base = blockIdx.x * 256;
  int f = t & 63, r = t >> 6;
  for (int i = r; i < 256; i += 4) {
    int n = base + i;
    if (n >= N) break;
    int g = batch[n];
    atomicAdd(&Ul[g * F + f], u[(size_t)n * F + f]);
    if (f == 0) { atomicAdd(&Vl[g], valn[n]); atomicAdd(&Cl[g], 1.f); }
  }
  __syncthreads();
  int last = min(base + 256, N) - 1;
  if (last < base) return;
  int gmin = batch[base], gmax = batch[last];
  int ng = gmax - gmin + 1;
  for (int idx = t; idx < ng * F; idx += 256) {
    int g = gmin + (idx >> 6), ff = idx & 63;
    atomicAdd(&Uacc[g * F + ff], Ul[g * F + ff]);
  }
  for (int idx = t; idx < ng; idx += 256) {
    int g = gmin + idx;
    atomicAdd(&valg[g], Vl[g]);
    atomicAdd(&cntg[g], Cl[g]);
  }
}

// ---------------- finalize ----------------
__global__ void k_polfin(const float* __restrict__ Uacc, const float* __restrict__ valg,
                         const float* __restrict__ cntg, const float* __restrict__ W_pol,
                         const float* __restrict__ b_pol, float* __restrict__ out, int G) {
  int i = blockIdx.x * blockDim.x + threadIdx.x;
  if (i < G * P) {
    int g = i >> 5, p = i & 31;
    float s = 0.f;
#pragma unroll
    for (int k = 0; k < F; ++k) s += Uacc[g * F + k] * W_pol[k * P + p];
    out[i] = s / fmaxf(cntg[g], 1.f) + b_pol[p];
  }
  if (i < G) out[(size_t)G * P + i] = valg[i];
}

extern "C" void kernel_launch(void* const* d_in, const int* in_sizes, int n_in,
                              void* d_out, int out_size, void* d_ws, size_t ws_size,
                              hipStream_t stream) {
  const float* x = (const float*)d_in[0];
  const int* ei = (const int*)d_in[1];
  const int* batch = (const int*)d_in[2];
  const float* W_in = (const float*)d_in[3];
  const float* b_in = (const float*)d_in[4];
  const float* W1 = (const float*)d_in[5];
  const float* b1 = (const float*)d_in[6];
  const float* Wl = (const float*)d_in[7];
  const float* bl = (const float*)d_in[8];
  const float* Wr = (const float*)d_in[9];
  const float* W_pol = (const float*)d_in[10];
  const float* b_pol = (const float*)d_in[11];
  float* out = (float*)d_out;

  const int N = in_sizes[0] / F;
  const int E = in_sizes[1] / 2;
  const int G = out_size / (P + 1);
  const int* esrc = ei;
  const int* edst = ei + E;
  const int NB = (N + 255) / 256;  // 196 for N=50000; k_scan_fin assumes NB <= 256

  char* ws = (char*)d_ws;
  size_t o = 0;
  auto alloc = [&](size_t bytes) {
    char* r = ws + o;
    o = (o + bytes + 255) & ~(size_t)255;
    return r;
  };
  // ---- zero-init zone ----
  char* zbase = ws;
  int* deg = (int*)alloc((size_t)N * 4);
  float* Uacc = (float*)alloc((size_t)G * F * 4);
  float* valg = (float*)alloc((size_t)G * 4);
  float* cntg = (float*)alloc((size_t)G * 4);
  size_t zbytes = o;  // multiple of 256
  // ---- rest ----
  int* off = (int*)alloc((size_t)(N + 1) * 4);
  int* cur = (int*)alloc((size_t)N * 4);
  float* dinv = (float*)alloc((size_t)N * 4);
  int* csr = (int*)alloc((size_t)E * 4);
  int* bsum = (int*)alloc(1024 * 4);
  float* valn = (float*)alloc((size_t)N * 4);
  unsigned* xs16 = (unsigned*)alloc((size_t)N * F * 2);  // bf16 x*dinv
  unsigned* t16 = (unsigned*)alloc((size_t)N * F * 2);   // bf16 dinv*h1
  unsigned* h16 = (unsigned*)alloc((size_t)N * F * 2);   // bf16 h2
  float* u = (float*)alloc((size_t)N * F * 4);           // fp32 policy-agg
  (void)ws_size; (void)n_in;

  const int bs = 256;
  int zn4 = (int)(zbytes / 16);
  k_zero<<<(zn4 + bs - 1) / bs, bs, 0, stream>>>((float4*)zbase, zn4);

  k_count_deg<<<1024, bs, 0, stream>>>(edst, deg, E);
  k_bsum<<<NB, bs, 0, stream>>>(deg, bsum, N);
  k_scan_fin<<<NB, bs, 0, stream>>>(deg, bsum, off, cur, dinv, N, NB);
  k_fill<<<2048, bs, 0, stream>>>(esrc, edst, cur, csr, E, N);

  // xs16 = bf16(dinv * x)
  k_scale16<<<2048, bs, 0, stream>>>(x, dinv, (uint2*)xs16, N);

  // GCN layers: 2048 blocks (8192 waves = full residency), 8-deep gather unroll
  k_gcn<true><<<2048, bs, 0, stream>>>(xs16, csr, off, dinv, W_in, b_in,
                                       (unsigned short*)t16, N);
  k_gcn<false><<<2048, bs, 0, stream>>>(t16, csr, off, dinv, W1, b1,
                                        (unsigned short*)h16, N);

  // fused MFConv + policy aggregation (4-deep, unfused pooling: proven-best split)
  int gBlocks = (N + 15) / 16;
  k_mfpol<<<gBlocks, bs, 0, stream>>>(h16, csr, off, dinv, Wl, bl, Wr, valn, u, N);

  int poolBlocks = (N + 255) / 256;
  k_pool2<<<poolBlocks, bs, 0, stream>>>(u, valn, batch, Uacc, valg, cntg, N);
  k_polfin<<<(G * P + bs - 1) / bs, bs, 0, stream>>>(Uacc, valg, cntg, W_pol, b_pol, out, G);
}